// Round 7
// baseline (358.763 us; speedup 1.0000x reference)
//
#include <hip/hip_runtime.h>
#include <hip/hip_bf16.h>
#include <cstdint>
#include <cstddef>

// VQKD forward: z = l2norm(tanh(X@W1+b1)@W2+b2); idx = argmin_k ||z-emb_k||^2 with
// emb = l2norm(codebook); z_q = emb[idx]; loss = mean((emb[idx]-z)^2).
// All GEMM-shaped work on f16 matrix cores with 2-way fp32 split (3 products):
// rel error ~3*2^-22 — argmin-safe (validated r3-r6, absmax <= 2.4e-4).

namespace {
constexpr int TOKENS = 8 * 4096;   // 32768
constexpr int DENC   = 768;
constexpr int DC     = 32;
constexpr int KC     = 8192;
constexpr int BM = 128, BN = 128, BK = 32;   // kgemm1 tile
constexpr int NSTEP = DENC / BK;             // 24
constexpr float WSCALE = 1024.0f;  // weight split scale (keeps lo out of subnormals)
constexpr float HSCALE = 512.0f;   // H split scale in kgemm2 (2^9 exact)
constexpr float SSCALE = 512.0f;   // z/emb split scale for ksearch (2^9 exact)
constexpr int SCH = 256;           // codes per LDS chunk in ksearch
}

typedef _Float16 f16x8 __attribute__((ext_vector_type(8)));
typedef float    f32x4 __attribute__((ext_vector_type(4)));

__device__ inline void split2(float v, _Float16& h, _Float16& l) {
  h = (_Float16)v;
  l = (_Float16)(v - (float)h);
}

__device__ inline void gload_lds16(const void* g, void* l) {
  __builtin_amdgcn_global_load_lds(
      (const __attribute__((address_space(1))) void*)g,
      (__attribute__((address_space(3))) void*)l, 16, 0, 0);
}

// ---------- K0a: split W1 (x1024) into fp16 hi/lo, TRANSPOSED to [N][K] ----------
__global__ void ksplitW(const float* __restrict__ W1,
                        _Float16* __restrict__ Wh, _Float16* __restrict__ Wl) {
  int n = blockIdx.y;
  int k = blockIdx.x * 256 + threadIdx.x;
  float w = W1[(size_t)k * DENC + n] * WSCALE;
  _Float16 h, l; split2(w, h, l);
  Wh[(size_t)n * DENC + k] = h;
  Wl[(size_t)n * DENC + k] = l;
}

// ---------- K0b: split W2 (x1024) into fp16 hi/lo, TRANSPOSED to [32][768] ----------
__global__ void ksplitW2(const float* __restrict__ W2,
                         _Float16* __restrict__ W2h, _Float16* __restrict__ W2l) {
  int i = blockIdx.x * 256 + threadIdx.x;    // 768*32
  int k = i >> 5, c = i & 31;
  float w = W2[(size_t)k * DC + c] * WSCALE;
  _Float16 h, l; split2(w, h, l);
  W2h[(size_t)c * DENC + k] = h;
  W2l[(size_t)c * DENC + k] = l;
}

// ---------- K1: normalize codebook; emit embn (fp32), split Eh/El (x512), se2 ----------
__global__ void knorm_codes(const float* __restrict__ cb,
                            float* __restrict__ embn, float* __restrict__ se2,
                            _Float16* __restrict__ Eh, _Float16* __restrict__ El) {
  int t = blockIdx.x * blockDim.x + threadIdx.x;
  int k = t >> 5, c = t & 31;
  float v = cb[(size_t)k * DC + c];
  float ss = v * v;
  #pragma unroll
  for (int m = 16; m >= 1; m >>= 1) ss += __shfl_xor(ss, m, 32);
  float nrm = fmaxf(sqrtf(ss), 1e-12f);
  float vn = v / nrm;
  embn[(size_t)k * DC + c] = vn;
  _Float16 h, l; split2(vn * SSCALE, h, l);
  Eh[(size_t)k * DC + c] = h;
  El[(size_t)k * DC + c] = l;
  float s2 = vn * vn;
  #pragma unroll
  for (int m = 16; m >= 1; m >>= 1) s2 += __shfl_xor(s2, m, 32);
  if (c == 0) se2[k] = s2 * (SSCALE * SSCALE);
}

// ---------- K2: H = tanh(X@W1+b1) fp32, MFMA split-2 ----------
// A: DIRECT from global per wave (2-way dup absorbed by L1/L2), split in-register.
// B: pre-split W1 planes via global_load_lds, double-buffered, 32 KB LDS only.
// One barrier/step. 3 blocks/CU (12 waves) so barrier/latency stalls of one
// block are covered by the other two (m114 implicit overlap).
__global__ __launch_bounds__(256, 3)
void kgemm1(const float* __restrict__ X,
            const _Float16* __restrict__ Wh, const _Float16* __restrict__ Wl,
            const float* __restrict__ bias1, float* __restrict__ H) {
  __shared__ __align__(16) _Float16 Bs[2][2][4][BN][8];  // [buf][pl][ko][col][8] = 32 KB

  // XCD-aware bijective swizzle (1536 blocks = 8 XCD * 192; 192 = 32 Mt * 6 Nt)
  const int bid = blockIdx.x;
  const int xcd = bid & 7;
  const int w   = bid >> 3;
  const int n_t = w % 6;
  const int m_t = xcd * 32 + w / 6;
  const int m0 = m_t * BM, n0 = n_t * BN;

  const int t    = threadIdx.x;
  const int lane = t & 63;
  const int wv   = t >> 6;
  const int wm   = wv >> 1, wn = wv & 1;
  const int lrow = lane & 15;
  const int lgrp = lane >> 4;

  // B staging role: wave wv stages plane (wv>>1), col-half (wv&1), 4 octets
  const int bpl = wv >> 1, bch = wv & 1;
  const _Float16* wlane = (bpl ? Wl : Wh) + (size_t)(n0 + bch * 64 + lane) * DENC;

  // A per-lane row base pointers: frag mf covers rows wm*64+mf*16+lrow,
  // lane's 8 k-elems at octet lgrp. One dwordx4 pair per frag per step.
  const float* xb[4];
  #pragma unroll
  for (int mf = 0; mf < 4; ++mf)
    xb[mf] = X + (size_t)(m0 + wm * 64 + mf * 16 + lrow) * DENC + lgrp * 8;

  f32x4 acc[4][4];
  #pragma unroll
  for (int i = 0; i < 4; ++i)
    #pragma unroll
    for (int j = 0; j < 4; ++j) acc[i][j] = (f32x4)0.0f;

  // prologue: stage B(0) into buf 0, load A(0) into pax
  float4 pax[8];
  #pragma unroll
  for (int o = 0; o < 4; ++o)
    gload_lds16(wlane + o * 8, &Bs[0][bpl][o][bch * 64 + lane][0]);
  #pragma unroll
  for (int mf = 0; mf < 4; ++mf) {
    pax[2 * mf]     = *(const float4*)(xb[mf]);
    pax[2 * mf + 1] = *(const float4*)(xb[mf] + 4);
  }

  for (int s = 0; s < NSTEP; ++s) {
    const int cur = s & 1;
    __syncthreads();   // drains vmcnt: Bs[cur] staged, pax loaded

    const bool more = (s + 1 < NSTEP);
    // 1. issue next B staging immediately (latency hides under whole step)
    if (more) {
      const _Float16* wsrc = wlane + (s + 1) * BK;
      #pragma unroll
      for (int o = 0; o < 4; ++o)
        gload_lds16(wsrc + o * 8, &Bs[cur ^ 1][bpl][o][bch * 64 + lane][0]);
    }

    // 2. split current A (registers) into MFMA fragments
    f16x8 fah[4], fal[4];
    #pragma unroll
    for (int mf = 0; mf < 4; ++mf) {
      float4 u = pax[2 * mf], v = pax[2 * mf + 1];
      float va[8] = {u.x, u.y, u.z, u.w, v.x, v.y, v.z, v.w};
      f16x8 hh, ll;
      #pragma unroll
      for (int e = 0; e < 8; ++e) { _Float16 h, l; split2(va[e], h, l); hh[e] = h; ll[e] = l; }
      fah[mf] = hh; fal[mf] = ll;
    }

    // 3. issue next A loads (WAR on pax is safe: splits already issued)
    if (more) {
      #pragma unroll
      for (int mf = 0; mf < 4; ++mf) {
        const float* p = xb[mf] + (s + 1) * BK;
        pax[2 * mf]     = *(const float4*)(p);
        pax[2 * mf + 1] = *(const float4*)(p + 4);
      }
    }

    // 4. MFMA phase: per-nf B frag reads (short liveness), 48 MFMA
    #pragma unroll
    for (int nf = 0; nf < 4; ++nf) {
      const int col = wn * 64 + nf * 16 + lrow;
      f16x8 nbh = *(const f16x8*)&Bs[cur][0][lgrp][col][0];
      f16x8 nbl = *(const f16x8*)&Bs[cur][1][lgrp][col][0];
      #pragma unroll
      for (int mf = 0; mf < 4; ++mf) {
        acc[mf][nf] = __builtin_amdgcn_mfma_f32_16x16x32_f16(fah[mf], nbh, acc[mf][nf], 0, 0, 0);
        acc[mf][nf] = __builtin_amdgcn_mfma_f32_16x16x32_f16(fah[mf], nbl, acc[mf][nf], 0, 0, 0);
        acc[mf][nf] = __builtin_amdgcn_mfma_f32_16x16x32_f16(fal[mf], nbh, acc[mf][nf], 0, 0, 0);
      }
    }
  }

  // epilogue: un-scale, bias, tanh, store fp32 (full 64B lines per 16-lane group)
  #pragma unroll
  for (int nf = 0; nf < 4; ++nf) {
    const int col = n0 + wn * 64 + nf * 16 + lrow;
    const float b = bias1[col];
    #pragma unroll
    for (int mf = 0; mf < 4; ++mf) {
      #pragma unroll
      for (int r = 0; r < 4; ++r) {
        const int row = m0 + wm * 64 + mf * 16 + lgrp * 4 + r;
        H[(size_t)row * DENC + col] = tanhf(acc[mf][nf][r] * (1.0f / WSCALE) + b);
      }
    }
  }
}

// ---------- K3: zn = l2norm(H @ W2 + b2), MFMA split-2, H split in-register ----------
// No LDS, no barriers. Wave = 32 tokens (2 mf x 2 nf), block = 2 waves.
__global__ __launch_bounds__(128, 4)
void kgemm2(const float* __restrict__ H,
            const _Float16* __restrict__ W2h, const _Float16* __restrict__ W2l,
            const float* __restrict__ b2, float* __restrict__ zn) {
  const int t = threadIdx.x, lane = t & 63, wv = t >> 6;
  const int lrow = lane & 15, lgrp = lane >> 4;
  const int tb = blockIdx.x * 64 + wv * 32;

  const float* ap[2];
  #pragma unroll
  for (int mf = 0; mf < 2; ++mf)
    ap[mf] = H + (size_t)(tb + mf * 16 + lrow) * DENC + lgrp * 8;
  const _Float16* bh_p[2]; const _Float16* bl_p[2];
  #pragma unroll
  for (int nf = 0; nf < 2; ++nf) {
    size_t coff = (size_t)(nf * 16 + lrow) * DENC + lgrp * 8;
    bh_p[nf] = W2h + coff; bl_p[nf] = W2l + coff;
  }

  f32x4 acc[2][2];
  #pragma unroll
  for (int i = 0; i < 2; ++i)
    #pragma unroll
    for (int j = 0; j < 2; ++j) acc[i][j] = (f32x4)0.0f;

  for (int s = 0; s < DENC / 32; ++s) {
    const int koff = s * 32;
    f16x8 a_h[2], a_l[2], b_h[2], b_l[2];
    #pragma unroll
    for (int mf = 0; mf < 2; ++mf) {
      float4 u = *(const float4*)(ap[mf] + koff);
      float4 v = *(const float4*)(ap[mf] + koff + 4);
      float va[8] = {u.x,u.y,u.z,u.w, v.x,v.y,v.z,v.w};
      f16x8 hh, ll;
      #pragma unroll
      for (int e = 0; e < 8; ++e) { _Float16 h, l; split2(va[e] * HSCALE, h, l); hh[e]=h; ll[e]=l; }
      a_h[mf] = hh; a_l[mf] = ll;
    }
    #pragma unroll
    for (int nf = 0; nf < 2; ++nf) {
      b_h[nf] = *(const f16x8*)(bh_p[nf] + koff);
      b_l[nf] = *(const f16x8*)(bl_p[nf] + koff);
    }
    #pragma unroll
    for (int mf = 0; mf < 2; ++mf)
      #pragma unroll
      for (int nf = 0; nf < 2; ++nf) {
        acc[mf][nf] = __builtin_amdgcn_mfma_f32_16x16x32_f16(a_h[mf], b_h[nf], acc[mf][nf], 0, 0, 0);
        acc[mf][nf] = __builtin_amdgcn_mfma_f32_16x16x32_f16(a_h[mf], b_l[nf], acc[mf][nf], 0, 0, 0);
        acc[mf][nf] = __builtin_amdgcn_mfma_f32_16x16x32_f16(a_l[mf], b_h[nf], acc[mf][nf], 0, 0, 0);
      }
  }

  // epilogue: z = acc/2^19 + b2; row-wise l2norm over 32 cols; store zn
  const float inv = 1.0f / (HSCALE * WSCALE);
  float bv[2];
  #pragma unroll
  for (int nf = 0; nf < 2; ++nf) bv[nf] = b2[nf * 16 + lrow];
  #pragma unroll
  for (int mf = 0; mf < 2; ++mf) {
    float z[2][4], ss[4];
    #pragma unroll
    for (int r = 0; r < 4; ++r) {
      #pragma unroll
      for (int nf = 0; nf < 2; ++nf) z[nf][r] = acc[mf][nf][r] * inv + bv[nf];
      float s2 = z[0][r] * z[0][r] + z[1][r] * z[1][r];
      #pragma unroll
      for (int m = 8; m >= 1; m >>= 1) s2 += __shfl_xor(s2, m, 16);
      ss[r] = s2;
    }
    #pragma unroll
    for (int r = 0; r < 4; ++r) {
      const int row = tb + mf * 16 + lgrp * 4 + r;
      float nrm = fmaxf(sqrtf(ss[r]), 1e-12f);
      #pragma unroll
      for (int nf = 0; nf < 2; ++nf)
        zn[(size_t)row * DC + nf * 16 + lrow] = z[nf][r] / nrm;
    }
  }
}

__device__ inline unsigned long long packkey(float d, int idx) {
  unsigned int u = __float_as_uint(d);
  u = (u & 0x80000000u) ? ~u : (u | 0x80000000u);
  return ((unsigned long long)u << 32) | (unsigned int)idx;
}

// ---------- K4: nearest code via MFMA split-2 GEMM + in-register argmin ----------
__global__ __launch_bounds__(256, 3)
void ksearch(const float* __restrict__ zn, const _Float16* __restrict__ Eh,
             const _Float16* __restrict__ El, const float* __restrict__ se2,
             unsigned long long* __restrict__ keys) {
  __shared__ __align__(16) _Float16 Bh[4][SCH][8], Bl[4][SCH][8];  // 32 KB
  __shared__ float ce2[SCH];
  const int t = threadIdx.x, lane = t & 63, wv = t >> 6;
  const int tb  = blockIdx.x * 256 + wv * 64;
  const int cb0 = blockIdx.y * 1024;
  const int lr = lane & 15, ko = lane >> 4;

  f16x8 azh[4], azl[4];
  #pragma unroll
  for (int m = 0; m < 4; ++m) {
    const float* zp = zn + (size_t)(tb + m * 16 + lr) * DC + ko * 8;
    float4 u = *(const float4*)zp, v = *(const float4*)(zp + 4);
    float vals[8] = {u.x, u.y, u.z, u.w, v.x, v.y, v.z, v.w};
    f16x8 hh, ll;
    #pragma unroll
    for (int e = 0; e < 8; ++e) {
      _Float16 h, l; split2(vals[e] * SSCALE, h, l);
      hh[e] = h; ll[e] = l;
    }
    azh[m] = hh; azl[m] = ll;
  }

  float best[4][4]; int bi[4][4];
  #pragma unroll
  for (int m = 0; m < 4; ++m)
    #pragma unroll
    for (int r = 0; r < 4; ++r) { best[m][r] = 3.4e38f; bi[m][r] = 0; }

  f16x8 pb[8]; float pe2;

  for (int ch = 0; ch < 4; ++ch) {
    const int cb = cb0 + ch * SCH;
    #pragma unroll
    for (int it = 0; it < 8; ++it) {
      const _Float16* src = (it < 4) ? Eh : El;
      pb[it] = *(const f16x8*)&src[(size_t)(cb + t) * DC + (it & 3) * 8];
    }
    pe2 = se2[cb + t];
    __syncthreads();
    #pragma unroll
    for (int it = 0; it < 8; ++it) {
      _Float16 (*B)[SCH][8] = (it < 4) ? Bh : Bl;
      *(f16x8*)&B[it & 3][t][0] = pb[it];
    }
    ce2[t] = pe2;
    __syncthreads();

    #pragma unroll 4
    for (int f = 0; f < SCH / 16; ++f) {
      f16x8 bh = *(const f16x8*)&Bh[ko][f * 16 + lr][0];
      f16x8 bl = *(const f16x8*)&Bl[ko][f * 16 + lr][0];
      float e2v = ce2[f * 16 + lr];
      int  code = cb + f * 16 + lr;
      #pragma unroll
      for (int m = 0; m < 4; ++m) {
        f32x4 a = (f32x4)0.0f;
        a = __builtin_amdgcn_mfma_f32_16x16x32_f16(azh[m], bh, a, 0, 0, 0);
        a = __builtin_amdgcn_mfma_f32_16x16x32_f16(azh[m], bl, a, 0, 0, 0);
        a = __builtin_amdgcn_mfma_f32_16x16x32_f16(azl[m], bh, a, 0, 0, 0);
        #pragma unroll
        for (int r = 0; r < 4; ++r) {
          float d = fmaf(-2.0f, a[r], e2v);
          bool c = d < best[m][r];
          best[m][r] = c ? d : best[m][r];
          bi[m][r]   = c ? code : bi[m][r];
        }
      }
    }
  }

  #pragma unroll
  for (int m = 0; m < 4; ++m)
    #pragma unroll
    for (int r = 0; r < 4; ++r) {
      float bd = best[m][r]; int ix = bi[m][r];
      #pragma unroll
      for (int s = 1; s < 16; s <<= 1) {
        float od = __shfl_xor(bd, s);
        int   oi = __shfl_xor(ix, s);
        if (od < bd || (od == bd && oi < ix)) { bd = od; ix = oi; }
      }
      if ((lane & 15) == 0) {
        int token = tb + m * 16 + (lane >> 4) * 4 + r;
        atomicMin(&keys[token], packkey(bd, ix));
      }
    }
}

// ---------- K5: gather emb[idx], straight-through z_q, loss, idx-as-float ----------
__global__ __launch_bounds__(1024)
void kfinal(const unsigned long long* __restrict__ keys,
            const float* __restrict__ zn, const float* __restrict__ embn,
            float* __restrict__ zq, float* __restrict__ loss,
            float* __restrict__ oidx) {
  __shared__ float red[32];
  int t = blockIdx.x * blockDim.x + threadIdx.x;
  int tok = t >> 5, c = t & 31;
  unsigned long long key = keys[tok];
  int idx = (int)(unsigned int)(key & 0xFFFFFFFFull);
  float q = embn[(size_t)idx * DC + c];
  float z = zn[t];
  zq[t] = z + (q - z);
  float d = q - z;
  float ss = d * d;
  #pragma unroll
  for (int m = 16; m >= 1; m >>= 1) ss += __shfl_xor(ss, m, 32);
  if (c == 0) {
    red[threadIdx.x >> 5] = ss;
    oidx[tok] = (float)idx;
  }
  __syncthreads();
  if (threadIdx.x < 32) {
    float v = red[threadIdx.x];
    #pragma unroll
    for (int m = 16; m >= 1; m >>= 1) v += __shfl_xor(v, m, 32);
    if (threadIdx.x == 0)
      atomicAdd(loss, v * (1.0f / (float)(TOKENS * DC)));
  }
}

extern "C" void kernel_launch(void* const* d_in, const int* in_sizes, int n_in,
                              void* d_out, int out_size, void* d_ws, size_t ws_size,
                              hipStream_t stream) {
  const float* X   = (const float*)d_in[0];
  const float* W1  = (const float*)d_in[1];
  const float* B1  = (const float*)d_in[2];
  const float* W2  = (const float*)d_in[3];
  const float* B2  = (const float*)d_in[4];
  const float* CB  = (const float*)d_in[5];

  float* out  = (float*)d_out;
  float* zq   = out;
  float* loss = out + (size_t)TOKENS * DC;
  float* oidx = loss + 1;

  char* ws = (char*)d_ws;
  size_t off = 0;
  float* H    = (float*)(ws + off); off += (size_t)TOKENS * DENC * 4;    // 100.7 MB
  float* zn   = (float*)(ws + off); off += (size_t)TOKENS * DC * 4;      // 4 MB
  float* embn = (float*)(ws + off); off += (size_t)KC * DC * 4;          // 1 MB
  float* se2  = (float*)(ws + off); off += (size_t)KC * 4;               // 32 KB
  _Float16* Eh = (_Float16*)(ws + off); off += (size_t)KC * DC * 2;      // 512 KB
  _Float16* El = (_Float16*)(ws + off); off += (size_t)KC * DC * 2;      // 512 KB
  unsigned long long* keys = (unsigned long long*)(ws + off);
  off += (size_t)TOKENS * 8;                                             // 256 KB
  _Float16* W2h = (_Float16*)(ws + off); off += (size_t)DC * DENC * 2;   // 48 KB
  _Float16* W2l = (_Float16*)(ws + off); off += (size_t)DC * DENC * 2;   // 48 KB
  // W1 split arrays alias the zn region (zn written only by kgemm2, which runs
  // after kgemm1 has consumed W1h/W1l): 2 * 768*768*2B = 2.25 MB < 4 MB.
  _Float16* W1h = (_Float16*)zn;
  _Float16* W1l = W1h + (size_t)DENC * DENC;

  hipMemsetAsync(loss, 0, sizeof(float), stream);
  hipMemsetAsync(keys, 0xFF, (size_t)TOKENS * 8, stream);

  ksplitW<<<dim3(DENC / 256, DENC), 256, 0, stream>>>(W1, W1h, W1l);
  ksplitW2<<<(DENC * DC) / 256, 256, 0, stream>>>(W2, W2h, W2l);
  knorm_codes<<<(KC * DC) / 256, 256, 0, stream>>>(CB, embn, se2, Eh, El);
  kgemm1<<<(TOKENS / BM) * (DENC / BN), 256, 0, stream>>>(X, W1h, W1l, B1, H);
  kgemm2<<<TOKENS / 64, 128, 0, stream>>>(H, W2h, W2l, B2, zn);
  ksearch<<<dim3(TOKENS / 256, KC / 1024), 256, 0, stream>>>(zn, Eh, El, se2, keys);
  kfinal<<<TOKENS * DC / 1024, 1024, 0, stream>>>(keys, zn, embn, zq, loss, oidx);
}

// Round 8
// 283.968 us; speedup vs baseline: 1.2634x; 1.2634x over previous
//
#include <hip/hip_runtime.h>
#include <hip/hip_bf16.h>
#include <cstdint>
#include <cstddef>

// VQKD forward: z = l2norm(tanh(X@W1+b1)@W2+b2); idx = argmin_k ||z-emb_k||^2 with
// emb = l2norm(codebook); z_q = emb[idx]; loss = mean((emb[idx]-z)^2).
// All GEMM-shaped work on f16 matrix cores with 2-way fp32 split (3 products):
// rel error ~3*2^-22 — argmin-safe (validated r3-r7, absmax <= 2.4e-4).

namespace {
constexpr int TOKENS = 8 * 4096;   // 32768
constexpr int DENC   = 768;
constexpr int DC     = 32;
constexpr int KC     = 8192;
constexpr int BM = 128, BN = 128, BK = 32;   // kgemm1 tile
constexpr int NSTEP = DENC / BK;             // 24
constexpr float WSCALE = 1024.0f;  // weight split scale (keeps lo out of subnormals)
constexpr float HSCALE = 512.0f;   // H split scale in kgemm2 (2^9 exact)
constexpr float SSCALE = 512.0f;   // z/emb split scale for ksearch (2^9 exact)
constexpr int SCH = 256;           // codes per LDS chunk in ksearch
}

typedef _Float16 f16x8 __attribute__((ext_vector_type(8)));
typedef float    f32x4 __attribute__((ext_vector_type(4)));

__device__ inline void split2(float v, _Float16& h, _Float16& l) {
  h = (_Float16)v;
  l = (_Float16)(v - (float)h);
}

__device__ inline void gload_lds16(const void* g, void* l) {
  __builtin_amdgcn_global_load_lds(
      (const __attribute__((address_space(1))) void*)g,
      (__attribute__((address_space(3))) void*)l, 16, 0, 0);
}

// ---------- K0a: split W1 (x1024) into fp16 hi/lo, TRANSPOSED to [N][K] ----------
__global__ void ksplitW(const float* __restrict__ W1,
                        _Float16* __restrict__ Wh, _Float16* __restrict__ Wl) {
  int n = blockIdx.y;
  int k = blockIdx.x * 256 + threadIdx.x;
  float w = W1[(size_t)k * DENC + n] * WSCALE;
  _Float16 h, l; split2(w, h, l);
  Wh[(size_t)n * DENC + k] = h;
  Wl[(size_t)n * DENC + k] = l;
}

// ---------- K0b: split W2 (x1024) into fp16 hi/lo, TRANSPOSED to [32][768] ----------
__global__ void ksplitW2(const float* __restrict__ W2,
                         _Float16* __restrict__ W2h, _Float16* __restrict__ W2l) {
  int i = blockIdx.x * 256 + threadIdx.x;    // 768*32
  int k = i >> 5, c = i & 31;
  float w = W2[(size_t)k * DC + c] * WSCALE;
  _Float16 h, l; split2(w, h, l);
  W2h[(size_t)c * DENC + k] = h;
  W2l[(size_t)c * DENC + k] = l;
}

// ---------- K1: normalize codebook; emit embn (fp32), split Eh/El (x512), se2 ----------
__global__ void knorm_codes(const float* __restrict__ cb,
                            float* __restrict__ embn, float* __restrict__ se2,
                            _Float16* __restrict__ Eh, _Float16* __restrict__ El) {
  int t = blockIdx.x * blockDim.x + threadIdx.x;
  int k = t >> 5, c = t & 31;
  float v = cb[(size_t)k * DC + c];
  float ss = v * v;
  #pragma unroll
  for (int m = 16; m >= 1; m >>= 1) ss += __shfl_xor(ss, m, 32);
  float nrm = fmaxf(sqrtf(ss), 1e-12f);
  float vn = v / nrm;
  embn[(size_t)k * DC + c] = vn;
  _Float16 h, l; split2(vn * SSCALE, h, l);
  Eh[(size_t)k * DC + c] = h;
  El[(size_t)k * DC + c] = l;
  float s2 = vn * vn;
  #pragma unroll
  for (int m = 16; m >= 1; m >>= 1) s2 += __shfl_xor(s2, m, 32);
  if (c == 0) se2[k] = s2 * (SSCALE * SSCALE);
}

// ---------- K2: H = tanh(X@W1+b1) fp32, MFMA split-2, m97-style schedule ----------
// Single 32 KB LDS buffer: A staged as RAW FP32 via global_load_lds (16 KB),
// B pre-split f16 planes via global_load_lds (16 KB). 2 barriers/step
// (stage -> barrier/vmcnt-drain -> compute -> barrier). A is split at
// fragment-read time (VALU was idle; removes r6's ds_write round-trip and
// bank conflicts). 3 blocks/CU so one block's staging drain hides under the
// other two blocks' MFMA (m114 implicit overlap).
__global__ __launch_bounds__(256, 3)
void kgemm1(const float* __restrict__ X,
            const _Float16* __restrict__ Wh, const _Float16* __restrict__ Wl,
            const float* __restrict__ bias1, float* __restrict__ H) {
  __shared__ __align__(16) float    As[4][BM][8];        // [ko][row][8 f32] = 16 KB
  __shared__ __align__(16) _Float16 Bsm[2][4][BN][8];    // [pl][ko][col][8] = 16 KB

  // XCD-aware bijective swizzle (1536 blocks = 8 XCD * 192; 192 = 32 Mt * 6 Nt)
  const int bid = blockIdx.x;
  const int xcd = bid & 7;
  const int w   = bid >> 3;
  const int n_t = w % 6;
  const int m_t = xcd * 32 + w / 6;
  const int m0 = m_t * BM, n0 = n_t * BN;

  const int t    = threadIdx.x;
  const int lane = t & 63;
  const int wv   = t >> 6;
  const int wm   = wv >> 1, wn = wv & 1;
  const int lrow = lane & 15;
  const int lgrp = lane >> 4;

  // Staging source pointers (per-lane global; LDS dest is wave-uniform base).
  // A round r (r=0..3): LDS bytes [r*4096 + wv*1024 + lane*16] <- f32 tile
  //   linear f = r*1024 + t*4 -> ko=r, row=t>>1, e=(t&1)*4.
  const float* xsrcA = X + (size_t)(m0 + wv * 32 + (lane >> 1)) * DENC + (lane & 1) * 4;
  // B round r: LDS bytes [r*4096 + wv*1024 + lane*16] <- f16 tile
  //   pl = r>>1, ko = (r&1)*2 + (wv>>1), col = (wv&1)*64 + lane.
  const int bko_half = wv >> 1;              // 0 or 1 -> +0 / +1 octet within pair
  const _Float16* bsrc[2] = {
    Wh + (size_t)(n0 + (wv & 1) * 64 + lane) * DENC,
    Wl + (size_t)(n0 + (wv & 1) * 64 + lane) * DENC };

  f32x4 acc[4][4];
  #pragma unroll
  for (int i = 0; i < 4; ++i)
    #pragma unroll
    for (int j = 0; j < 4; ++j) acc[i][j] = (f32x4)0.0f;

  char* AsB  = (char*)&As[0][0][0];
  char* BsB  = (char*)&Bsm[0][0][0][0];

  // stage step s into the (single) buffer: 8 gload_lds per wave
  auto stage = [&](int s) {
    const int k0 = s * BK;
    #pragma unroll
    for (int r = 0; r < 4; ++r)
      gload_lds16(xsrcA + k0 + r * 8, AsB + r * 4096 + wv * 1024);
    #pragma unroll
    for (int r = 0; r < 4; ++r) {
      const int pl = r >> 1;
      const int ko = (r & 1) * 2 + bko_half;
      gload_lds16(bsrc[pl] + k0 + ko * 8, BsB + r * 4096 + wv * 1024);
    }
  };

  stage(0);
  for (int s = 0; s < NSTEP; ++s) {
    __syncthreads();   // vmcnt drain: buffer fully staged

    // A fragments: read fp32, split in-register (dup 2-way across wm-waves; VALU idle)
    f16x8 fah[4], fal[4];
    #pragma unroll
    for (int mf = 0; mf < 4; ++mf) {
      const int row = wm * 64 + mf * 16 + lrow;
      float4 u = *(const float4*)&As[lgrp][row][0];
      float4 v = *(const float4*)&As[lgrp][row][4];
      float va[8] = {u.x, u.y, u.z, u.w, v.x, v.y, v.z, v.w};
      f16x8 hh, ll;
      #pragma unroll
      for (int e = 0; e < 8; ++e) { _Float16 h, l; split2(va[e], h, l); hh[e] = h; ll[e] = l; }
      fah[mf] = hh; fal[mf] = ll;
    }

    // MFMA phase: per-nf B frag reads, 48 MFMA
    #pragma unroll
    for (int nf = 0; nf < 4; ++nf) {
      const int col = wn * 64 + nf * 16 + lrow;
      f16x8 nbh = *(const f16x8*)&Bsm[0][lgrp][col][0];
      f16x8 nbl = *(const f16x8*)&Bsm[1][lgrp][col][0];
      #pragma unroll
      for (int mf = 0; mf < 4; ++mf) {
        acc[mf][nf] = __builtin_amdgcn_mfma_f32_16x16x32_f16(fah[mf], nbh, acc[mf][nf], 0, 0, 0);
        acc[mf][nf] = __builtin_amdgcn_mfma_f32_16x16x32_f16(fah[mf], nbl, acc[mf][nf], 0, 0, 0);
        acc[mf][nf] = __builtin_amdgcn_mfma_f32_16x16x32_f16(fal[mf], nbh, acc[mf][nf], 0, 0, 0);
      }
    }

    __syncthreads();   // all LDS reads of this step done
    if (s + 1 < NSTEP) stage(s + 1);   // overwrite buffer; drained at next top-barrier
  }

  // epilogue: un-scale, bias, tanh, store fp32 (full 64B lines per 16-lane group)
  #pragma unroll
  for (int nf = 0; nf < 4; ++nf) {
    const int col = n0 + wn * 64 + nf * 16 + lrow;
    const float b = bias1[col];
    #pragma unroll
    for (int mf = 0; mf < 4; ++mf) {
      #pragma unroll
      for (int r = 0; r < 4; ++r) {
        const int row = m0 + wm * 64 + mf * 16 + lgrp * 4 + r;
        H[(size_t)row * DENC + col] = tanhf(acc[mf][nf][r] * (1.0f / WSCALE) + b);
      }
    }
  }
}

// ---------- K3: zn = l2norm(H @ W2 + b2), MFMA split-2, H split in-register ----------
// No LDS, no barriers. Wave = 32 tokens (2 mf x 2 nf), block = 2 waves.
__global__ __launch_bounds__(128, 4)
void kgemm2(const float* __restrict__ H,
            const _Float16* __restrict__ W2h, const _Float16* __restrict__ W2l,
            const float* __restrict__ b2, float* __restrict__ zn) {
  const int t = threadIdx.x, lane = t & 63, wv = t >> 6;
  const int lrow = lane & 15, lgrp = lane >> 4;
  const int tb = blockIdx.x * 64 + wv * 32;

  const float* ap[2];
  #pragma unroll
  for (int mf = 0; mf < 2; ++mf)
    ap[mf] = H + (size_t)(tb + mf * 16 + lrow) * DENC + lgrp * 8;
  const _Float16* bh_p[2]; const _Float16* bl_p[2];
  #pragma unroll
  for (int nf = 0; nf < 2; ++nf) {
    size_t coff = (size_t)(nf * 16 + lrow) * DENC + lgrp * 8;
    bh_p[nf] = W2h + coff; bl_p[nf] = W2l + coff;
  }

  f32x4 acc[2][2];
  #pragma unroll
  for (int i = 0; i < 2; ++i)
    #pragma unroll
    for (int j = 0; j < 2; ++j) acc[i][j] = (f32x4)0.0f;

  for (int s = 0; s < DENC / 32; ++s) {
    const int koff = s * 32;
    f16x8 a_h[2], a_l[2], b_h[2], b_l[2];
    #pragma unroll
    for (int mf = 0; mf < 2; ++mf) {
      float4 u = *(const float4*)(ap[mf] + koff);
      float4 v = *(const float4*)(ap[mf] + koff + 4);
      float va[8] = {u.x,u.y,u.z,u.w, v.x,v.y,v.z,v.w};
      f16x8 hh, ll;
      #pragma unroll
      for (int e = 0; e < 8; ++e) { _Float16 h, l; split2(va[e] * HSCALE, h, l); hh[e]=h; ll[e]=l; }
      a_h[mf] = hh; a_l[mf] = ll;
    }
    #pragma unroll
    for (int nf = 0; nf < 2; ++nf) {
      b_h[nf] = *(const f16x8*)(bh_p[nf] + koff);
      b_l[nf] = *(const f16x8*)(bl_p[nf] + koff);
    }
    #pragma unroll
    for (int mf = 0; mf < 2; ++mf)
      #pragma unroll
      for (int nf = 0; nf < 2; ++nf) {
        acc[mf][nf] = __builtin_amdgcn_mfma_f32_16x16x32_f16(a_h[mf], b_h[nf], acc[mf][nf], 0, 0, 0);
        acc[mf][nf] = __builtin_amdgcn_mfma_f32_16x16x32_f16(a_h[mf], b_l[nf], acc[mf][nf], 0, 0, 0);
        acc[mf][nf] = __builtin_amdgcn_mfma_f32_16x16x32_f16(a_l[mf], b_h[nf], acc[mf][nf], 0, 0, 0);
      }
  }

  // epilogue: z = acc/2^19 + b2; row-wise l2norm over 32 cols; store zn
  const float inv = 1.0f / (HSCALE * WSCALE);
  float bv[2];
  #pragma unroll
  for (int nf = 0; nf < 2; ++nf) bv[nf] = b2[nf * 16 + lrow];
  #pragma unroll
  for (int mf = 0; mf < 2; ++mf) {
    float z[2][4], ss[4];
    #pragma unroll
    for (int r = 0; r < 4; ++r) {
      #pragma unroll
      for (int nf = 0; nf < 2; ++nf) z[nf][r] = acc[mf][nf][r] * inv + bv[nf];
      float s2 = z[0][r] * z[0][r] + z[1][r] * z[1][r];
      #pragma unroll
      for (int m = 8; m >= 1; m >>= 1) s2 += __shfl_xor(s2, m, 16);
      ss[r] = s2;
    }
    #pragma unroll
    for (int r = 0; r < 4; ++r) {
      const int row = tb + mf * 16 + lgrp * 4 + r;
      float nrm = fmaxf(sqrtf(ss[r]), 1e-12f);
      #pragma unroll
      for (int nf = 0; nf < 2; ++nf)
        zn[(size_t)row * DC + nf * 16 + lrow] = z[nf][r] / nrm;
    }
  }
}

__device__ inline unsigned long long packkey(float d, int idx) {
  unsigned int u = __float_as_uint(d);
  u = (u & 0x80000000u) ? ~u : (u | 0x80000000u);
  return ((unsigned long long)u << 32) | (unsigned int)idx;
}

// ---------- K4: nearest code via MFMA split-2 GEMM + in-register argmin ----------
__global__ __launch_bounds__(256, 3)
void ksearch(const float* __restrict__ zn, const _Float16* __restrict__ Eh,
             const _Float16* __restrict__ El, const float* __restrict__ se2,
             unsigned long long* __restrict__ keys) {
  __shared__ __align__(16) _Float16 Bh[4][SCH][8], Bl[4][SCH][8];  // 32 KB
  __shared__ float ce2[SCH];
  const int t = threadIdx.x, lane = t & 63, wv = t >> 6;
  const int tb  = blockIdx.x * 256 + wv * 64;
  const int cb0 = blockIdx.y * 1024;
  const int lr = lane & 15, ko = lane >> 4;

  f16x8 azh[4], azl[4];
  #pragma unroll
  for (int m = 0; m < 4; ++m) {
    const float* zp = zn + (size_t)(tb + m * 16 + lr) * DC + ko * 8;
    float4 u = *(const float4*)zp, v = *(const float4*)(zp + 4);
    float vals[8] = {u.x, u.y, u.z, u.w, v.x, v.y, v.z, v.w};
    f16x8 hh, ll;
    #pragma unroll
    for (int e = 0; e < 8; ++e) {
      _Float16 h, l; split2(vals[e] * SSCALE, h, l);
      hh[e] = h; ll[e] = l;
    }
    azh[m] = hh; azl[m] = ll;
  }

  float best[4][4]; int bi[4][4];
  #pragma unroll
  for (int m = 0; m < 4; ++m)
    #pragma unroll
    for (int r = 0; r < 4; ++r) { best[m][r] = 3.4e38f; bi[m][r] = 0; }

  f16x8 pb[8]; float pe2;

  for (int ch = 0; ch < 4; ++ch) {
    const int cb = cb0 + ch * SCH;
    #pragma unroll
    for (int it = 0; it < 8; ++it) {
      const _Float16* src = (it < 4) ? Eh : El;
      pb[it] = *(const f16x8*)&src[(size_t)(cb + t) * DC + (it & 3) * 8];
    }
    pe2 = se2[cb + t];
    __syncthreads();
    #pragma unroll
    for (int it = 0; it < 8; ++it) {
      _Float16 (*B)[SCH][8] = (it < 4) ? Bh : Bl;
      *(f16x8*)&B[it & 3][t][0] = pb[it];
    }
    ce2[t] = pe2;
    __syncthreads();

    #pragma unroll 4
    for (int f = 0; f < SCH / 16; ++f) {
      f16x8 bh = *(const f16x8*)&Bh[ko][f * 16 + lr][0];
      f16x8 bl = *(const f16x8*)&Bl[ko][f * 16 + lr][0];
      float e2v = ce2[f * 16 + lr];
      int  code = cb + f * 16 + lr;
      #pragma unroll
      for (int m = 0; m < 4; ++m) {
        f32x4 a = (f32x4)0.0f;
        a = __builtin_amdgcn_mfma_f32_16x16x32_f16(azh[m], bh, a, 0, 0, 0);
        a = __builtin_amdgcn_mfma_f32_16x16x32_f16(azh[m], bl, a, 0, 0, 0);
        a = __builtin_amdgcn_mfma_f32_16x16x32_f16(azl[m], bh, a, 0, 0, 0);
        #pragma unroll
        for (int r = 0; r < 4; ++r) {
          float d = fmaf(-2.0f, a[r], e2v);
          bool c = d < best[m][r];
          best[m][r] = c ? d : best[m][r];
          bi[m][r]   = c ? code : bi[m][r];
        }
      }
    }
  }

  #pragma unroll
  for (int m = 0; m < 4; ++m)
    #pragma unroll
    for (int r = 0; r < 4; ++r) {
      float bd = best[m][r]; int ix = bi[m][r];
      #pragma unroll
      for (int s = 1; s < 16; s <<= 1) {
        float od = __shfl_xor(bd, s);
        int   oi = __shfl_xor(ix, s);
        if (od < bd || (od == bd && oi < ix)) { bd = od; ix = oi; }
      }
      if ((lane & 15) == 0) {
        int token = tb + m * 16 + (lane >> 4) * 4 + r;
        atomicMin(&keys[token], packkey(bd, ix));
      }
    }
}

// ---------- K5: gather emb[idx], straight-through z_q, loss, idx-as-float ----------
__global__ __launch_bounds__(1024)
void kfinal(const unsigned long long* __restrict__ keys,
            const float* __restrict__ zn, const float* __restrict__ embn,
            float* __restrict__ zq, float* __restrict__ loss,
            float* __restrict__ oidx) {
  __shared__ float red[32];
  int t = blockIdx.x * blockDim.x + threadIdx.x;
  int tok = t >> 5, c = t & 31;
  unsigned long long key = keys[tok];
  int idx = (int)(unsigned int)(key & 0xFFFFFFFFull);
  float q = embn[(size_t)idx * DC + c];
  float z = zn[t];
  zq[t] = z + (q - z);
  float d = q - z;
  float ss = d * d;
  #pragma unroll
  for (int m = 16; m >= 1; m >>= 1) ss += __shfl_xor(ss, m, 32);
  if (c == 0) {
    red[threadIdx.x >> 5] = ss;
    oidx[tok] = (float)idx;
  }
  __syncthreads();
  if (threadIdx.x < 32) {
    float v = red[threadIdx.x];
    #pragma unroll
    for (int m = 16; m >= 1; m >>= 1) v += __shfl_xor(v, m, 32);
    if (threadIdx.x == 0)
      atomicAdd(loss, v * (1.0f / (float)(TOKENS * DC)));
  }
}

extern "C" void kernel_launch(void* const* d_in, const int* in_sizes, int n_in,
                              void* d_out, int out_size, void* d_ws, size_t ws_size,
                              hipStream_t stream) {
  const float* X   = (const float*)d_in[0];
  const float* W1  = (const float*)d_in[1];
  const float* B1  = (const float*)d_in[2];
  const float* W2  = (const float*)d_in[3];
  const float* B2  = (const float*)d_in[4];
  const float* CB  = (const float*)d_in[5];

  float* out  = (float*)d_out;
  float* zq   = out;
  float* loss = out + (size_t)TOKENS * DC;
  float* oidx = loss + 1;

  char* ws = (char*)d_ws;
  size_t off = 0;
  float* H    = (float*)(ws + off); off += (size_t)TOKENS * DENC * 4;    // 100.7 MB
  float* zn   = (float*)(ws + off); off += (size_t)TOKENS * DC * 4;      // 4 MB
  float* embn = (float*)(ws + off); off += (size_t)KC * DC * 4;          // 1 MB
  float* se2  = (float*)(ws + off); off += (size_t)KC * 4;               // 32 KB
  _Float16* Eh = (_Float16*)(ws + off); off += (size_t)KC * DC * 2;      // 512 KB
  _Float16* El = (_Float16*)(ws + off); off += (size_t)KC * DC * 2;      // 512 KB
  unsigned long long* keys = (unsigned long long*)(ws + off);
  off += (size_t)TOKENS * 8;                                             // 256 KB
  _Float16* W2h = (_Float16*)(ws + off); off += (size_t)DC * DENC * 2;   // 48 KB
  _Float16* W2l = (_Float16*)(ws + off); off += (size_t)DC * DENC * 2;   // 48 KB
  // W1 split arrays alias the zn region (zn written only by kgemm2, which runs
  // after kgemm1 has consumed W1h/W1l): 2 * 768*768*2B = 2.25 MB < 4 MB.
  _Float16* W1h = (_Float16*)zn;
  _Float16* W1l = W1h + (size_t)DENC * DENC;

  hipMemsetAsync(loss, 0, sizeof(float), stream);
  hipMemsetAsync(keys, 0xFF, (size_t)TOKENS * 8, stream);

  ksplitW<<<dim3(DENC / 256, DENC), 256, 0, stream>>>(W1, W1h, W1l);
  ksplitW2<<<(DENC * DC) / 256, 256, 0, stream>>>(W2, W2h, W2l);
  knorm_codes<<<(KC * DC) / 256, 256, 0, stream>>>(CB, embn, se2, Eh, El);
  kgemm1<<<(TOKENS / BM) * (DENC / BN), 256, 0, stream>>>(X, W1h, W1l, B1, H);
  kgemm2<<<TOKENS / 64, 128, 0, stream>>>(H, W2h, W2l, B2, zn);
  ksearch<<<dim3(TOKENS / 256, KC / 1024), 256, 0, stream>>>(zn, Eh, El, se2, keys);
  kfinal<<<TOKENS * DC / 1024, 1024, 0, stream>>>(keys, zn, embn, zq, loss, oidx);
}

// Round 9
// 262.932 us; speedup vs baseline: 1.3645x; 1.0800x over previous
//
#include <hip/hip_runtime.h>
#include <hip/hip_bf16.h>
#include <cstdint>
#include <cstddef>

// VQKD forward: z = l2norm(tanh(X@W1+b1)@W2+b2); idx = argmin_k ||z-emb_k||^2 with
// emb = l2norm(codebook); z_q = emb[idx]; loss = mean((emb[idx]-z)^2).
// All GEMM-shaped work on f16 matrix cores with 2-way fp32 split (3 products):
// rel error ~3*2^-22 — argmin-safe (validated r3-r8, absmax <= 2.4e-4).
// r9: GEMM2 fused into GEMM1's epilogue (H never materialized; 6 n-tile partial
// z's summed by kreduce), A-read bank-conflict XOR swizzle, 4 blocks/CU.

namespace {
constexpr int TOKENS = 8 * 4096;   // 32768
constexpr int DENC   = 768;
constexpr int DC     = 32;
constexpr int KC     = 8192;
constexpr int BM = 128, BN = 128, BK = 32;   // kfused tile
constexpr int NSTEP = DENC / BK;             // 24
constexpr int NT    = DENC / BN;             // 6 n-tiles
constexpr float WSCALE = 1024.0f;  // weight split scale (keeps lo out of subnormals)
constexpr float HSCALE = 512.0f;   // H split scale for fused GEMM2 (2^9 exact)
constexpr float SSCALE = 512.0f;   // z/emb split scale for ksearch (2^9 exact)
constexpr int SCH = 256;           // codes per LDS chunk in ksearch
}

typedef _Float16 f16x8 __attribute__((ext_vector_type(8)));
typedef float    f32x4 __attribute__((ext_vector_type(4)));

__device__ inline void split2(float v, _Float16& h, _Float16& l) {
  h = (_Float16)v;
  l = (_Float16)(v - (float)h);
}

__device__ inline void gload_lds16(const void* g, void* l) {
  __builtin_amdgcn_global_load_lds(
      (const __attribute__((address_space(1))) void*)g,
      (__attribute__((address_space(3))) void*)l, 16, 0, 0);
}

// ---------- K0a: split W1 (x1024) into fp16 hi/lo, TRANSPOSED to [N][K] ----------
__global__ void ksplitW(const float* __restrict__ W1,
                        _Float16* __restrict__ Wh, _Float16* __restrict__ Wl) {
  int n = blockIdx.y;
  int k = blockIdx.x * 256 + threadIdx.x;
  float w = W1[(size_t)k * DENC + n] * WSCALE;
  _Float16 h, l; split2(w, h, l);
  Wh[(size_t)n * DENC + k] = h;
  Wl[(size_t)n * DENC + k] = l;
}

// ---------- K0b: split W2 (x1024) into fp16 hi/lo, TRANSPOSED to [32][768] ----------
__global__ void ksplitW2(const float* __restrict__ W2,
                         _Float16* __restrict__ W2h, _Float16* __restrict__ W2l) {
  int i = blockIdx.x * 256 + threadIdx.x;    // 768*32
  int k = i >> 5, c = i & 31;
  float w = W2[(size_t)k * DC + c] * WSCALE;
  _Float16 h, l; split2(w, h, l);
  W2h[(size_t)c * DENC + k] = h;
  W2l[(size_t)c * DENC + k] = l;
}

// ---------- K1: normalize codebook; emit embn (fp32), split Eh/El (x512), se2 ----------
__global__ void knorm_codes(const float* __restrict__ cb,
                            float* __restrict__ embn, float* __restrict__ se2,
                            _Float16* __restrict__ Eh, _Float16* __restrict__ El) {
  int t = blockIdx.x * blockDim.x + threadIdx.x;
  int k = t >> 5, c = t & 31;
  float v = cb[(size_t)k * DC + c];
  float ss = v * v;
  #pragma unroll
  for (int m = 16; m >= 1; m >>= 1) ss += __shfl_xor(ss, m, 32);
  float nrm = fmaxf(sqrtf(ss), 1e-12f);
  float vn = v / nrm;
  embn[(size_t)k * DC + c] = vn;
  _Float16 h, l; split2(vn * SSCALE, h, l);
  Eh[(size_t)k * DC + c] = h;
  El[(size_t)k * DC + c] = l;
  float s2 = vn * vn;
  #pragma unroll
  for (int m = 16; m >= 1; m >>= 1) s2 += __shfl_xor(s2, m, 32);
  if (c == 0) se2[k] = s2 * (SSCALE * SSCALE);
}

// ---------- K2: fused H-tile GEMM + tanh + partial GEMM2 -> zpart ----------
// Main loop = r8's proven m97-style schedule (A fp32 + B f16 planes via
// global_load_lds, single 32 KB buffer, 2 barriers/step) + A-read XOR swizzle
// (source-permuted for gload_lds linear dest; 4-way -> free 2-way).
// Epilogue: tanh'd tile -> LDS (fp32, 64-col halves) -> MFMA vs W2 slice ->
// partial z per n-tile. H never touches HBM.
__global__ __launch_bounds__(256, 4)
void kfused(const float* __restrict__ X,
            const _Float16* __restrict__ Wh, const _Float16* __restrict__ Wl,
            const float* __restrict__ bias1,
            const _Float16* __restrict__ W2h, const _Float16* __restrict__ W2l,
            float* __restrict__ zpart) {
  // union: main loop {As fp32 16KB @0, Bsm f16 16KB @16384} | epilogue Hs[128][68] f32
  __shared__ __align__(16) char smem[34816];
  char*     AsB = smem;                       // [ko(4)][row(128)][8 f32] w/ slot swizzle
  _Float16* Bsm = (_Float16*)(smem + 16384);  // [pl(2)][ko(4)][col(128)][8]
  float (*Hs)[68] = (float(*)[68])smem;       // epilogue: [row(128)][col(64)+pad4]

  // XCD-aware bijective swizzle (1536 blocks = 8 XCD * 192; 192 = 32 Mt * 6 Nt)
  const int bid = blockIdx.x;
  const int xcd = bid & 7;
  const int w   = bid >> 3;
  const int n_t = w % 6;
  const int m_t = xcd * 32 + w / 6;
  const int m0 = m_t * BM, n0 = n_t * BN;

  const int t    = threadIdx.x;
  const int lane = t & 63;
  const int wv   = t >> 6;
  const int wm   = wv >> 1, wn = wv & 1;
  const int lrow = lane & 15;
  const int lgrp = lane >> 4;

  // A staging source (pre-swizzled so linear gload_lds dest == swizzled layout):
  // lane covers row = wv*32 + (lane>>1); physical slot (lane&1) must hold
  // logical 16B-half e' = (lane&1) ^ ((row>>2)&1) = (lane&1) ^ ((lane>>3)&1).
  const int ae = (lane & 1) ^ ((lane >> 3) & 1);
  const float* xsrcA = X + (size_t)(m0 + wv * 32 + (lane >> 1)) * DENC + ae * 4;
  // B staging: wave wv stages plane (wv>>1), col-half (wv&1)
  const _Float16* bsrc[2] = {
    Wh + (size_t)(n0 + (wv & 1) * 64 + lane) * DENC,
    Wl + (size_t)(n0 + (wv & 1) * 64 + lane) * DENC };
  const int bko_half = wv >> 1;

  f32x4 acc[4][4];
  #pragma unroll
  for (int i = 0; i < 4; ++i)
    #pragma unroll
    for (int j = 0; j < 4; ++j) acc[i][j] = (f32x4)0.0f;

  char* BsB = (char*)Bsm;
  auto stage = [&](int s) {
    const int k0 = s * BK;
    #pragma unroll
    for (int r = 0; r < 4; ++r)
      gload_lds16(xsrcA + k0 + r * 8, AsB + r * 4096 + wv * 1024);
    #pragma unroll
    for (int r = 0; r < 4; ++r) {
      const int pl = r >> 1;
      const int ko = (r & 1) * 2 + bko_half;
      gload_lds16(bsrc[pl] + k0 + ko * 8, BsB + r * 4096 + wv * 1024);
    }
  };

  stage(0);
  for (int s = 0; s < NSTEP; ++s) {
    __syncthreads();   // vmcnt drain: buffer fully staged

    // A fragments: swizzled-slot fp32 reads, split in-register
    f16x8 fah[4], fal[4];
    #pragma unroll
    for (int mf = 0; mf < 4; ++mf) {
      const int row = wm * 64 + mf * 16 + lrow;
      const int b   = (row >> 2) & 1;
      const char* base = AsB + lgrp * 4096 + row * 32;
      float4 u = *(const float4*)(base + ((0 ^ b) << 4));   // elems 0-3
      float4 v = *(const float4*)(base + ((1 ^ b) << 4));   // elems 4-7
      float va[8] = {u.x, u.y, u.z, u.w, v.x, v.y, v.z, v.w};
      f16x8 hh, ll;
      #pragma unroll
      for (int e = 0; e < 8; ++e) { _Float16 h, l; split2(va[e], h, l); hh[e] = h; ll[e] = l; }
      fah[mf] = hh; fal[mf] = ll;
    }

    // MFMA phase
    #pragma unroll
    for (int nf = 0; nf < 4; ++nf) {
      const int col = wn * 64 + nf * 16 + lrow;
      f16x8 nbh = *(const f16x8*)&Bsm[((0 * 4 + lgrp) * BN + col) * 8];
      f16x8 nbl = *(const f16x8*)&Bsm[((1 * 4 + lgrp) * BN + col) * 8];
      #pragma unroll
      for (int mf = 0; mf < 4; ++mf) {
        acc[mf][nf] = __builtin_amdgcn_mfma_f32_16x16x32_f16(fah[mf], nbh, acc[mf][nf], 0, 0, 0);
        acc[mf][nf] = __builtin_amdgcn_mfma_f32_16x16x32_f16(fah[mf], nbl, acc[mf][nf], 0, 0, 0);
        acc[mf][nf] = __builtin_amdgcn_mfma_f32_16x16x32_f16(fal[mf], nbh, acc[mf][nf], 0, 0, 0);
      }
    }

    __syncthreads();   // all LDS reads of this step done
    if (s + 1 < NSTEP) stage(s + 1);
  }

  // ---- epilogue part 1: tanh in place (true H values) ----
  {
    float bv[4];
    #pragma unroll
    for (int nf = 0; nf < 4; ++nf) bv[nf] = bias1[n0 + wn * 64 + nf * 16 + lrow];
    #pragma unroll
    for (int mf = 0; mf < 4; ++mf)
      #pragma unroll
      for (int nf = 0; nf < 4; ++nf)
        #pragma unroll
        for (int r = 0; r < 4; ++r)
          acc[mf][nf][r] = tanhf(acc[mf][nf][r] * (1.0f / WSCALE) + bv[nf]);
  }

  // ---- epilogue part 2: fused GEMM2 partial (z[128 tok x 32] over this n-tile) ----
  f32x4 zacc[2][2];
  #pragma unroll
  for (int i = 0; i < 2; ++i)
    #pragma unroll
    for (int j = 0; j < 2; ++j) zacc[i][j] = (f32x4)0.0f;

  #pragma unroll
  for (int h = 0; h < 2; ++h) {
    __syncthreads();                 // Hs region free (main loop / prev half done)
    if (wn == h) {                   // this wave's cols live in half h
      #pragma unroll
      for (int mf = 0; mf < 4; ++mf)
        #pragma unroll
        for (int nf = 0; nf < 4; ++nf)
          #pragma unroll
          for (int r = 0; r < 4; ++r)
            Hs[wm * 64 + mf * 16 + lgrp * 4 + r][nf * 16 + lrow] = acc[mf][nf][r];
    }
    __syncthreads();
    // each wave: 32 token-rows (wv*32..+31), all 32 z-cols, k = this 64-col half
    #pragma unroll
    for (int ks = 0; ks < 2; ++ks) {
      const int koct = ks * 4 + lgrp;          // k-octet within the half (0..7)
      f16x8 bfh[2], bfl[2];
      #pragma unroll
      for (int nf = 0; nf < 2; ++nf) {
        const int c = nf * 16 + lrow;
        const size_t kg = (size_t)c * DENC + n0 + h * 64 + koct * 8;
        bfh[nf] = *(const f16x8*)&W2h[kg];
        bfl[nf] = *(const f16x8*)&W2l[kg];
      }
      #pragma unroll
      for (int mf = 0; mf < 2; ++mf) {
        const float* hp = &Hs[wv * 32 + mf * 16 + lrow][koct * 8];
        float4 u = *(const float4*)hp, v = *(const float4*)(hp + 4);
        float va[8] = {u.x, u.y, u.z, u.w, v.x, v.y, v.z, v.w};
        f16x8 hh, ll;
        #pragma unroll
        for (int e = 0; e < 8; ++e) { _Float16 hx, lx; split2(va[e] * HSCALE, hx, lx); hh[e] = hx; ll[e] = lx; }
        #pragma unroll
        for (int nf = 0; nf < 2; ++nf) {
          zacc[mf][nf] = __builtin_amdgcn_mfma_f32_16x16x32_f16(hh, bfh[nf], zacc[mf][nf], 0, 0, 0);
          zacc[mf][nf] = __builtin_amdgcn_mfma_f32_16x16x32_f16(hh, bfl[nf], zacc[mf][nf], 0, 0, 0);
          zacc[mf][nf] = __builtin_amdgcn_mfma_f32_16x16x32_f16(ll, bfh[nf], zacc[mf][nf], 0, 0, 0);
        }
      }
    }
  }

  // write partial z (scaled domain; kreduce applies 1/2^19 + bias + l2norm)
  float* zp = zpart + (size_t)n_t * TOKENS * DC;
  #pragma unroll
  for (int mf = 0; mf < 2; ++mf)
    #pragma unroll
    for (int r = 0; r < 4; ++r) {
      const int row = m0 + wv * 32 + mf * 16 + lgrp * 4 + r;
      #pragma unroll
      for (int nf = 0; nf < 2; ++nf)
        zp[(size_t)row * DC + nf * 16 + lrow] = zacc[mf][nf][r];
    }
}

// ---------- K3: zn = l2norm(sum of 6 partials / 2^19 + b2) ----------
__global__ void kreduce(const float* __restrict__ zpart, const float* __restrict__ b2,
                        float* __restrict__ zn) {
  int t = blockIdx.x * blockDim.x + threadIdx.x;   // TOKENS*DC
  int c = t & 31;
  float s = 0.0f;
  #pragma unroll
  for (int nt = 0; nt < NT; ++nt) s += zpart[(size_t)nt * TOKENS * DC + t];
  float z = s * (1.0f / (HSCALE * WSCALE)) + b2[c];
  float ss = z * z;
  #pragma unroll
  for (int m = 16; m >= 1; m >>= 1) ss += __shfl_xor(ss, m, 32);
  float nrm = fmaxf(sqrtf(ss), 1e-12f);
  zn[t] = z / nrm;
}

__device__ inline unsigned long long packkey(float d, int idx) {
  unsigned int u = __float_as_uint(d);
  u = (u & 0x80000000u) ? ~u : (u | 0x80000000u);
  return ((unsigned long long)u << 32) | (unsigned int)idx;
}

// ---------- K4: nearest code via MFMA split-2 GEMM + in-register argmin ----------
__global__ __launch_bounds__(256, 4)
void ksearch(const float* __restrict__ zn, const _Float16* __restrict__ Eh,
             const _Float16* __restrict__ El, const float* __restrict__ se2,
             unsigned long long* __restrict__ keys) {
  __shared__ __align__(16) _Float16 Bh[4][SCH][8], Bl[4][SCH][8];  // 32 KB
  __shared__ float ce2[SCH];
  const int t = threadIdx.x, lane = t & 63, wv = t >> 6;
  const int tb  = blockIdx.x * 256 + wv * 64;
  const int cb0 = blockIdx.y * 1024;
  const int lr = lane & 15, ko = lane >> 4;

  f16x8 azh[4], azl[4];
  #pragma unroll
  for (int m = 0; m < 4; ++m) {
    const float* zp = zn + (size_t)(tb + m * 16 + lr) * DC + ko * 8;
    float4 u = *(const float4*)zp, v = *(const float4*)(zp + 4);
    float vals[8] = {u.x, u.y, u.z, u.w, v.x, v.y, v.z, v.w};
    f16x8 hh, ll;
    #pragma unroll
    for (int e = 0; e < 8; ++e) {
      _Float16 h, l; split2(vals[e] * SSCALE, h, l);
      hh[e] = h; ll[e] = l;
    }
    azh[m] = hh; azl[m] = ll;
  }

  float best[4][4]; int bi[4][4];
  #pragma unroll
  for (int m = 0; m < 4; ++m)
    #pragma unroll
    for (int r = 0; r < 4; ++r) { best[m][r] = 3.4e38f; bi[m][r] = 0; }

  f16x8 pb[8]; float pe2;

  for (int ch = 0; ch < 4; ++ch) {
    const int cb = cb0 + ch * SCH;
    #pragma unroll
    for (int it = 0; it < 8; ++it) {
      const _Float16* src = (it < 4) ? Eh : El;
      pb[it] = *(const f16x8*)&src[(size_t)(cb + t) * DC + (it & 3) * 8];
    }
    pe2 = se2[cb + t];
    __syncthreads();
    #pragma unroll
    for (int it = 0; it < 8; ++it) {
      _Float16 (*B)[SCH][8] = (it < 4) ? Bh : Bl;
      *(f16x8*)&B[it & 3][t][0] = pb[it];
    }
    ce2[t] = pe2;
    __syncthreads();

    #pragma unroll 4
    for (int f = 0; f < SCH / 16; ++f) {
      f16x8 bh = *(const f16x8*)&Bh[ko][f * 16 + lr][0];
      f16x8 bl = *(const f16x8*)&Bl[ko][f * 16 + lr][0];
      float e2v = ce2[f * 16 + lr];
      int  code = cb + f * 16 + lr;
      #pragma unroll
      for (int m = 0; m < 4; ++m) {
        f32x4 a = (f32x4)0.0f;
        a = __builtin_amdgcn_mfma_f32_16x16x32_f16(azh[m], bh, a, 0, 0, 0);
        a = __builtin_amdgcn_mfma_f32_16x16x32_f16(azh[m], bl, a, 0, 0, 0);
        a = __builtin_amdgcn_mfma_f32_16x16x32_f16(azl[m], bh, a, 0, 0, 0);
        #pragma unroll
        for (int r = 0; r < 4; ++r) {
          float d = fmaf(-2.0f, a[r], e2v);
          bool c = d < best[m][r];
          best[m][r] = c ? d : best[m][r];
          bi[m][r]   = c ? code : bi[m][r];
        }
      }
    }
  }

  #pragma unroll
  for (int m = 0; m < 4; ++m)
    #pragma unroll
    for (int r = 0; r < 4; ++r) {
      float bd = best[m][r]; int ix = bi[m][r];
      #pragma unroll
      for (int s = 1; s < 16; s <<= 1) {
        float od = __shfl_xor(bd, s);
        int   oi = __shfl_xor(ix, s);
        if (od < bd || (od == bd && oi < ix)) { bd = od; ix = oi; }
      }
      if ((lane & 15) == 0) {
        int token = tb + m * 16 + (lane >> 4) * 4 + r;
        atomicMin(&keys[token], packkey(bd, ix));
      }
    }
}

// ---------- K5: gather emb[idx], straight-through z_q, loss, idx-as-float ----------
__global__ __launch_bounds__(1024)
void kfinal(const unsigned long long* __restrict__ keys,
            const float* __restrict__ zn, const float* __restrict__ embn,
            float* __restrict__ zq, float* __restrict__ loss,
            float* __restrict__ oidx) {
  __shared__ float red[32];
  int t = blockIdx.x * blockDim.x + threadIdx.x;
  int tok = t >> 5, c = t & 31;
  unsigned long long key = keys[tok];
  int idx = (int)(unsigned int)(key & 0xFFFFFFFFull);
  float q = embn[(size_t)idx * DC + c];
  float z = zn[t];
  zq[t] = z + (q - z);
  float d = q - z;
  float ss = d * d;
  #pragma unroll
  for (int m = 16; m >= 1; m >>= 1) ss += __shfl_xor(ss, m, 32);
  if (c == 0) {
    red[threadIdx.x >> 5] = ss;
    oidx[tok] = (float)idx;
  }
  __syncthreads();
  if (threadIdx.x < 32) {
    float v = red[threadIdx.x];
    #pragma unroll
    for (int m = 16; m >= 1; m >>= 1) v += __shfl_xor(v, m, 32);
    if (threadIdx.x == 0)
      atomicAdd(loss, v * (1.0f / (float)(TOKENS * DC)));
  }
}

extern "C" void kernel_launch(void* const* d_in, const int* in_sizes, int n_in,
                              void* d_out, int out_size, void* d_ws, size_t ws_size,
                              hipStream_t stream) {
  const float* X   = (const float*)d_in[0];
  const float* W1  = (const float*)d_in[1];
  const float* B1  = (const float*)d_in[2];
  const float* W2  = (const float*)d_in[3];
  const float* B2  = (const float*)d_in[4];
  const float* CB  = (const float*)d_in[5];

  float* out  = (float*)d_out;
  float* zq   = out;
  float* loss = out + (size_t)TOKENS * DC;
  float* oidx = loss + 1;

  char* ws = (char*)d_ws;
  size_t off = 0;
  float* zpart = (float*)(ws + off); off += (size_t)NT * TOKENS * DC * 4;  // 25.2 MB
  float* zn   = (float*)(ws + off); off += (size_t)TOKENS * DC * 4;        // 4 MB
  float* embn = (float*)(ws + off); off += (size_t)KC * DC * 4;            // 1 MB
  float* se2  = (float*)(ws + off); off += (size_t)KC * 4;                 // 32 KB
  _Float16* Eh = (_Float16*)(ws + off); off += (size_t)KC * DC * 2;        // 512 KB
  _Float16* El = (_Float16*)(ws + off); off += (size_t)KC * DC * 2;        // 512 KB
  unsigned long long* keys = (unsigned long long*)(ws + off);
  off += (size_t)TOKENS * 8;                                               // 256 KB
  _Float16* W2h = (_Float16*)(ws + off); off += (size_t)DC * DENC * 2;     // 48 KB
  _Float16* W2l = (_Float16*)(ws + off); off += (size_t)DC * DENC * 2;     // 48 KB
  // W1 split arrays alias the zn region (zn written only by kreduce, which runs
  // after kfused has consumed W1h/W1l): 2 * 768*768*2B = 2.25 MB < 4 MB.
  _Float16* W1h = (_Float16*)zn;
  _Float16* W1l = W1h + (size_t)DENC * DENC;

  hipMemsetAsync(loss, 0, sizeof(float), stream);
  hipMemsetAsync(keys, 0xFF, (size_t)TOKENS * 8, stream);

  ksplitW<<<dim3(DENC / 256, DENC), 256, 0, stream>>>(W1, W1h, W1l);
  ksplitW2<<<(DENC * DC) / 256, 256, 0, stream>>>(W2, W2h, W2l);
  knorm_codes<<<(KC * DC) / 256, 256, 0, stream>>>(CB, embn, se2, Eh, El);
  kfused<<<(TOKENS / BM) * (DENC / BN), 256, 0, stream>>>(X, W1h, W1l, B1, W2h, W2l, zpart);
  kreduce<<<TOKENS * DC / 256, 256, 0, stream>>>(zpart, B2, zn);
  ksearch<<<dim3(TOKENS / 256, KC / 1024), 256, 0, stream>>>(zn, Eh, El, se2, keys);
  kfinal<<<TOKENS * DC / 1024, 1024, 0, stream>>>(keys, zn, embn, zq, loss, oidx);
}